// Round 3
// baseline (4198.844 us; speedup 1.0000x reference)
//
#include <hip/hip_runtime.h>

// LightGCN / SGL propagation: out = mean_{l=0..3}(A^l x), A given as COO (nnz=6M),
// N=500k nodes, D=64. Wave-per-edge atomic SpMM baseline.

#define DIM 64

__global__ void init_concat(const float4* __restrict__ ue,
                            const float4* __restrict__ ie,
                            float4* __restrict__ cur,
                            float4* __restrict__ out,
                            int nu4, int n4) {
    int i = blockIdx.x * blockDim.x + threadIdx.x;
    int stride = gridDim.x * blockDim.x;
    for (; i < n4; i += stride) {
        float4 v = (i < nu4) ? ue[i] : ie[i - nu4];
        cur[i] = v;
        out[i] = v;
    }
}

__global__ void spmm_atomic(const float* __restrict__ val,
                            const int* __restrict__ row,
                            const int* __restrict__ col,
                            const float* __restrict__ cur,
                            float* __restrict__ next,
                            int nnz) {
    const int lane = threadIdx.x & 63;
    int wid = (int)(((size_t)blockIdx.x * blockDim.x + threadIdx.x) >> 6);
    int nw = (int)(((size_t)gridDim.x * blockDim.x) >> 6);
    for (int e = wid; e < nnz; e += nw) {
        int r = row[e];
        int c = col[e];
        float v = val[e];
        float x = cur[(size_t)c * DIM + lane];
        atomicAdd(next + (size_t)r * DIM + lane, v * x);
    }
}

__global__ void accum_scale(float4* __restrict__ out,
                            const float4* __restrict__ x,
                            int n4, float scale) {
    int i = blockIdx.x * blockDim.x + threadIdx.x;
    int stride = gridDim.x * blockDim.x;
    for (; i < n4; i += stride) {
        float4 a = out[i];
        float4 b = x[i];
        a.x = (a.x + b.x) * scale;
        a.y = (a.y + b.y) * scale;
        a.z = (a.z + b.z) * scale;
        a.w = (a.w + b.w) * scale;
        out[i] = a;
    }
}

extern "C" void kernel_launch(void* const* d_in, const int* in_sizes, int n_in,
                              void* d_out, int out_size, void* d_ws, size_t ws_size,
                              hipStream_t stream) {
    const float* ue  = (const float*)d_in[0];   // user_emb  [U*64]
    const float* ie  = (const float*)d_in[1];   // item_emb  [I*64]
    const float* val = (const float*)d_in[2];   // adj_val   [nnz]
    const int*   row = (const int*)d_in[3];     // adj_row   [nnz]
    const int*   col = (const int*)d_in[4];     // adj_col   [nnz]
    // d_in[5] = num_layers (scalar, fixed at 3 for this problem)

    const int nu  = in_sizes[0];       // U*D
    const int nnz = in_sizes[2];
    const int n   = out_size;          // N*D
    const int n4  = n >> 2;

    float* out  = (float*)d_out;
    float* bufA = (float*)d_ws;
    float* bufB = bufA + n;

    const int blk = 256;
    const int grid_copy = 4096;        // grid-stride streaming passes
    const int grid_spmm = 4096;        // 16384 waves, ~366 edges each

    init_concat<<<grid_copy, blk, 0, stream>>>(
        (const float4*)ue, (const float4*)ie,
        (float4*)bufA, (float4*)out, nu >> 2, n4);

    float* cur = bufA;
    float* nxt = bufB;
    const int L = 3;
    for (int l = 0; l < L; ++l) {
        hipMemsetAsync(nxt, 0, (size_t)n * sizeof(float), stream);
        spmm_atomic<<<grid_spmm, blk, 0, stream>>>(val, row, col, cur, nxt, nnz);
        float scale = (l == L - 1) ? 0.25f : 1.0f;
        accum_scale<<<grid_copy, blk, 0, stream>>>(
            (float4*)out, (const float4*)nxt, n4, scale);
        float* t = cur; cur = nxt; nxt = t;
    }
}

// Round 4
// 1904.384 us; speedup vs baseline: 2.2048x; 2.2048x over previous
//
#include <hip/hip_runtime.h>

// LightGCN / SGL propagation, CSR-rebuilt-on-device version.
// out = mean_{l=0..3}(A^l x); A: COO nnz=6M, N=500k, D=64.
// Pipeline: histogram -> 2-level scan -> scatter to (col,val) pairs ->
//           3x wave-per-row gather SpMM with fused accumulate (no atomics on D-wide data).

#define DIM 64

__global__ void init_concat(const float4* __restrict__ ue,
                            const float4* __restrict__ ie,
                            float4* __restrict__ cur,
                            float4* __restrict__ out,
                            int nu4, int n4) {
    int i = blockIdx.x * blockDim.x + threadIdx.x;
    int stride = gridDim.x * blockDim.x;
    for (; i < n4; i += stride) {
        float4 v = (i < nu4) ? ue[i] : ie[i - nu4];
        cur[i] = v;
        out[i] = v;
    }
}

__global__ void hist_rows(const int* __restrict__ row, int* __restrict__ deg, int nnz) {
    int i = blockIdx.x * blockDim.x + threadIdx.x;
    int stride = gridDim.x * blockDim.x;
    for (; i < nnz; i += stride) atomicAdd(&deg[row[i]], 1);
}

// Block-local exclusive scan: 256 threads x 4 items = 1024 elements/block.
__global__ void scan_local(const int* __restrict__ deg, int* __restrict__ excl,
                           int* __restrict__ partials, int n) {
    __shared__ int sdata[256];
    const int tid = threadIdx.x;
    int base = blockIdx.x * 1024 + tid * 4;
    int v0 = (base + 0 < n) ? deg[base + 0] : 0;
    int v1 = (base + 1 < n) ? deg[base + 1] : 0;
    int v2 = (base + 2 < n) ? deg[base + 2] : 0;
    int v3 = (base + 3 < n) ? deg[base + 3] : 0;
    int s = v0 + v1 + v2 + v3;
    sdata[tid] = s;
    __syncthreads();
    // Hillis-Steele inclusive scan over 256 thread sums
    for (int off = 1; off < 256; off <<= 1) {
        int t = (tid >= off) ? sdata[tid - off] : 0;
        __syncthreads();
        sdata[tid] += t;
        __syncthreads();
    }
    int texcl = sdata[tid] - s;   // exclusive prefix of this thread
    if (tid == 255) partials[blockIdx.x] = sdata[255];
    int run = texcl;
    if (base + 0 < n) excl[base + 0] = run; run += v0;
    if (base + 1 < n) excl[base + 1] = run; run += v1;
    if (base + 2 < n) excl[base + 2] = run; run += v2;
    if (base + 3 < n) excl[base + 3] = run;
}

// Single-block exclusive scan of block partials (nb <= 512), writes total to *total_out.
__global__ void scan_partials(int* __restrict__ partials, int* __restrict__ total_out, int nb) {
    __shared__ int sdata[512];
    const int tid = threadIdx.x;
    int orig = (tid < nb) ? partials[tid] : 0;
    sdata[tid] = orig;
    __syncthreads();
    for (int off = 1; off < 512; off <<= 1) {
        int t = (tid >= off) ? sdata[tid - off] : 0;
        __syncthreads();
        sdata[tid] += t;
        __syncthreads();
    }
    if (tid < nb) partials[tid] = sdata[tid] - orig;  // exclusive
    if (tid == 511) *total_out = sdata[511];          // = nnz
}

__global__ void add_offsets(int* __restrict__ row_ptr, int* __restrict__ cursor,
                            const int* __restrict__ offsets, int n) {
    int i = blockIdx.x * blockDim.x + threadIdx.x;
    int stride = gridDim.x * blockDim.x;
    for (; i < n; i += stride) {
        int v = row_ptr[i] + offsets[i >> 10];
        row_ptr[i] = v;
        cursor[i] = v;
    }
}

__global__ void scatter_edges(const int* __restrict__ row, const int* __restrict__ col,
                              const float* __restrict__ val, int* __restrict__ cursor,
                              int2* __restrict__ pack, int nnz) {
    int i = blockIdx.x * blockDim.x + threadIdx.x;
    int stride = gridDim.x * blockDim.x;
    for (; i < nnz; i += stride) {
        int r = row[i];
        int pos = atomicAdd(&cursor[r], 1);
        pack[pos] = make_int2(col[i], __float_as_int(val[i]));
    }
}

// Wave-per-row SpMM: 4 groups of 16 lanes; lane sl owns dims [4*sl,4*sl+4) as float4.
// Fused: out[r] = (out[r] + rowsum) * scale ; optionally nxt[r] = rowsum.
__global__ void spmm_csr(const int* __restrict__ row_ptr, const int2* __restrict__ pack,
                         const float4* __restrict__ cur, float4* __restrict__ out,
                         float4* __restrict__ nxt, int n_rows, float scale, int write_next) {
    const int lane = threadIdx.x & 63;
    const int g = lane >> 4;
    const int sl = lane & 15;
    int wid = (int)(((size_t)blockIdx.x * blockDim.x + threadIdx.x) >> 6);
    int nw = (int)(((size_t)gridDim.x * blockDim.x) >> 6);
    for (int r = wid; r < n_rows; r += nw) {
        int start = row_ptr[r];
        int end = row_ptr[r + 1];
        float4 acc = make_float4(0.f, 0.f, 0.f, 0.f);
        for (int e = start + g; e < end; e += 4) {
            int2 p = pack[e];
            float v = __int_as_float(p.y);
            float4 x = cur[p.x * 16 + sl];
            acc.x += v * x.x;
            acc.y += v * x.y;
            acc.z += v * x.z;
            acc.w += v * x.w;
        }
        // sum the 4 edge-groups: lanes differing in bits 4,5 hold partials of same dims
        acc.x += __shfl_xor(acc.x, 16); acc.y += __shfl_xor(acc.y, 16);
        acc.z += __shfl_xor(acc.z, 16); acc.w += __shfl_xor(acc.w, 16);
        acc.x += __shfl_xor(acc.x, 32); acc.y += __shfl_xor(acc.y, 32);
        acc.z += __shfl_xor(acc.z, 32); acc.w += __shfl_xor(acc.w, 32);
        if (lane < 16) {
            int o = r * 16 + sl;
            if (write_next) nxt[o] = acc;
            float4 t = out[o];
            t.x = (t.x + acc.x) * scale;
            t.y = (t.y + acc.y) * scale;
            t.z = (t.z + acc.z) * scale;
            t.w = (t.w + acc.w) * scale;
            out[o] = t;
        }
    }
}

extern "C" void kernel_launch(void* const* d_in, const int* in_sizes, int n_in,
                              void* d_out, int out_size, void* d_ws, size_t ws_size,
                              hipStream_t stream) {
    const float* ue  = (const float*)d_in[0];
    const float* ie  = (const float*)d_in[1];
    const float* val = (const float*)d_in[2];
    const int*   row = (const int*)d_in[3];
    const int*   col = (const int*)d_in[4];

    const int nu     = in_sizes[0];          // U*D
    const int nnz    = in_sizes[2];
    const int n      = out_size;             // N*D
    const int n4     = n >> 2;
    const int n_rows = n / DIM;

    float* out  = (float*)d_out;

    // workspace layout
    float* bufA    = (float*)d_ws;                       // 128 MB
    float* bufB    = bufA + n;                           // 128 MB
    int2*  pack    = (int2*)(bufB + n);                  // nnz*8 B
    int*   deg     = (int*)(pack + nnz);                 // N
    int*   row_ptr = deg + n_rows;                       // N+1
    int*   cursor  = row_ptr + n_rows + 1;               // N
    int*   partials= cursor + n_rows;                    // <=512

    const int blk = 256;
    const int grid_copy = 4096;
    const int grid_edge = 2048;
    const int grid_spmm = 4096;
    const int nb_scan = (n_rows + 1023) / 1024;          // 489 for N=500k

    hipMemsetAsync(deg, 0, (size_t)n_rows * sizeof(int), stream);
    init_concat<<<grid_copy, blk, 0, stream>>>(
        (const float4*)ue, (const float4*)ie,
        (float4*)bufA, (float4*)out, nu >> 2, n4);

    hist_rows<<<grid_edge, blk, 0, stream>>>(row, deg, nnz);
    scan_local<<<nb_scan, 256, 0, stream>>>(deg, row_ptr, partials, n_rows);
    scan_partials<<<1, 512, 0, stream>>>(partials, row_ptr + n_rows, nb_scan);
    add_offsets<<<grid_copy, blk, 0, stream>>>(row_ptr, cursor, partials, n_rows);
    scatter_edges<<<grid_edge, blk, 0, stream>>>(row, col, val, cursor, pack, nnz);

    float* cur = bufA;
    float* nxt = bufB;
    const int L = 3;
    for (int l = 0; l < L; ++l) {
        float scale = (l == L - 1) ? 0.25f : 1.0f;
        int write_next = (l != L - 1);
        spmm_csr<<<grid_spmm, blk, 0, stream>>>(
            row_ptr, pack, (const float4*)cur, (float4*)out,
            (float4*)nxt, n_rows, scale, write_next);
        float* t = cur; cur = nxt; nxt = t;
    }
}